// Round 5
// baseline (355.245 us; speedup 1.0000x reference)
//
#include <hip/hip_runtime.h>

typedef float v4f __attribute__((ext_vector_type(4)));
typedef int   v4i __attribute__((ext_vector_type(4)));

#define NB0 24
#define NB1 12
#define NB2 16
#define NC_TOTAL (NB0 + NB1 + NB2)   // 52

struct KParams {
    float c[NC_TOTAL];   // bin centers, host-computed — bit-exact vs JAX f32 (proven r1/r3/r4)
    float inv_w[3];
};

// ---- numeric path: VERBATIM from rounds 1/3/4 (absmax == 0.0) — do not touch ----
__device__ __forceinline__ float geo_dist(float a, float c, float two_pi) {
    float diff = fabsf(a - c);
    float alt  = two_pi - diff;
    return fminf(diff, alt);
}

template <int N>
__device__ __forceinline__ void quant1(float a, const float* __restrict__ sc,
                                       float inv_w, float pi_f, float two_pi,
                                       int& idx_out, float& q_out) {
    float u = (a + pi_f) * inv_w;
    int k = (int)floorf(u);
    k = (k < 0) ? 0 : ((k > N - 1) ? (N - 1) : k);
    int km = (k == 0) ? (N - 1) : (k - 1);
    int kp = (k == N - 1) ? 0 : (k + 1);

    float dk = geo_dist(a, sc[k],  two_pi);
    float dm = geo_dist(a, sc[km], two_pi);
    float dp = geo_dist(a, sc[kp], two_pi);

    int best = k; float bd = dk;
    if (dm < bd || (dm == bd && km < best)) { bd = dm; best = km; }
    if (dp < bd || (dp == bd && kp < best)) { bd = dp; best = kp; }

    idx_out = best;
    float t = sc[best] - a;
    q_out = a + t;
}

__device__ __forceinline__ void do_row(const float* __restrict__ sc,
                                       float iw0, float iw1, float iw2,
                                       float pi_f, float two_pi,
                                       float a0, float a1, float a2, int mt_i, int mr_i,
                                       float& q0, float& q1, float& q2,
                                       float& i0, float& i1, float& i2) {
    int b0, b1, b2; float t0, t1, t2;
    quant1<NB0>(a0, sc,             iw0, pi_f, two_pi, b0, t0);
    quant1<NB1>(a1, sc + NB0,       iw1, pi_f, two_pi, b1, t1);
    quant1<NB2>(a2, sc + NB0 + NB1, iw2, pi_f, two_pi, b2, t2);
    bool mt = (mt_i != 0), mr = (mr_i != 0);
    q0 = mt ? 0.0f : t0;
    q1 = mr ? 0.0f : t1;
    q2 = t2;
    i0 = mt ? (float)NB0 : (float)b0;
    i1 = mr ? (float)NB1 : (float)b1;
    i2 = (float)b2;
}
// ---------------------------------------------------------------------------

#define WAVE_LDS 6144

// PROBE BUILD (round 5): identical memory/numeric structure to round 4, but the
// whole pass runs TWICE (rep loop). Second pass recomputes and rewrites the same
// values — output identical, dispatch duration ~2x so the kernel surfaces in the
// rocprof top-5 with its own counters. k4 = dur5 - dur4; fixed = 2*dur4 - dur5.
__global__ void __launch_bounds__(256) cyclicvq_kernel(
    const float* __restrict__ angles,
    const int*   __restrict__ mask,
    float* __restrict__ out_q,
    float* __restrict__ out_i,
    int nrows, KParams p)
{
    __shared__ float sc[NC_TOTAL];
    __shared__ unsigned char smem[4 * WAVE_LDS];
    if (threadIdx.x < NC_TOTAL) sc[threadIdx.x] = p.c[threadIdx.x];

    const float pi_f   = (float)3.141592653589793;
    const float two_pi = (float)6.283185307179586;
    const float iw0 = p.inv_w[0], iw1 = p.inv_w[1], iw2 = p.inv_w[2];

    const int wave = threadIdx.x >> 6;
    const int lane = threadIdx.x & 63;
    const int block_row0 = blockIdx.x << 10;          // 1024 rows per block

    for (int rep = 0; rep < 2; ++rep) {
        if (block_row0 + 1024 <= nrows) {
            // ------------- fast path: fully coalesced via LDS transpose -------------
            const int wave_row0 = block_row0 + (wave << 8);
            const int ga = (wave_row0 * 3) >> 2;
            const int gm = (wave_row0 >> 1);

            const v4f* av = (const v4f*)angles;
            v4f A0 = __builtin_nontemporal_load(av + ga + lane);
            v4f A1 = __builtin_nontemporal_load(av + ga + 64 + lane);
            v4f A2 = __builtin_nontemporal_load(av + ga + 128 + lane);

            const v4i* mv = (const v4i*)mask;
            v4i M0 = __builtin_nontemporal_load(mv + gm + 2 * lane);
            v4i M1 = __builtin_nontemporal_load(mv + gm + 2 * lane + 1);

            unsigned char* wbase = smem + wave * WAVE_LDS;
            v4f* sA = (v4f*)wbase;
            sA[lane]       = A0;
            sA[64 + lane]  = A1;
            sA[128 + lane] = A2;
            __syncthreads();

            const float* fA = (const float*)wbase;
            v4f a0 = ((const v4f*)(fA + 12 * lane))[0];
            v4f a1 = ((const v4f*)(fA + 12 * lane))[1];
            v4f a2 = ((const v4f*)(fA + 12 * lane))[2];

            float q00,q01,q02,i00,i01,i02;
            float q10,q11,q12,i10,i11,i12;
            float q20,q21,q22,i20,i21,i22;
            float q30,q31,q32,i30,i31,i32;
            do_row(sc, iw0,iw1,iw2, pi_f,two_pi, a0.x, a0.y, a0.z, M0.x, M0.y,
                   q00,q01,q02, i00,i01,i02);
            do_row(sc, iw0,iw1,iw2, pi_f,two_pi, a0.w, a1.x, a1.y, M0.z, M0.w,
                   q10,q11,q12, i10,i11,i12);
            do_row(sc, iw0,iw1,iw2, pi_f,two_pi, a1.z, a1.w, a2.x, M1.x, M1.y,
                   q20,q21,q22, i20,i21,i22);
            do_row(sc, iw0,iw1,iw2, pi_f,two_pi, a2.y, a2.z, a2.w, M1.z, M1.w,
                   q30,q31,q32, i30,i31,i32);

            float* fQ = (float*)wbase;
            float* fI = (float*)(wbase + 3072);
            ((v4f*)(fQ + 12 * lane))[0] = (v4f){q00,q01,q02,q10};
            ((v4f*)(fQ + 12 * lane))[1] = (v4f){q11,q12,q20,q21};
            ((v4f*)(fQ + 12 * lane))[2] = (v4f){q22,q30,q31,q32};
            ((v4f*)(fI + 12 * lane))[0] = (v4f){i00,i01,i02,i10};
            ((v4f*)(fI + 12 * lane))[1] = (v4f){i11,i12,i20,i21};
            ((v4f*)(fI + 12 * lane))[2] = (v4f){i22,i30,i31,i32};
            __syncthreads();

            const v4f* sQ = (const v4f*)wbase;
            const v4f* sI = (const v4f*)(wbase + 3072);
            v4f* oq = (v4f*)out_q;
            v4f* oi = (v4f*)out_i;
            __builtin_nontemporal_store(sQ[lane],        oq + ga + lane);
            __builtin_nontemporal_store(sQ[64 + lane],   oq + ga + 64 + lane);
            __builtin_nontemporal_store(sQ[128 + lane],  oq + ga + 128 + lane);
            __builtin_nontemporal_store(sI[lane],        oi + ga + lane);
            __builtin_nontemporal_store(sI[64 + lane],   oi + ga + 64 + lane);
            __builtin_nontemporal_store(sI[128 + lane],  oi + ga + 128 + lane);
            __syncthreads();   // rep isolation: LDS reuse across reps
        } else {
            // ------------- tail path: scalar (not taken at 4096x2048) --------------
            __syncthreads();
            for (int row = block_row0 + (int)threadIdx.x; row < nrows; row += 256) {
                long long r3 = (long long)row * 3;
                long long r2 = (long long)row * 2;
                float q0,q1,q2,i0,i1,i2;
                do_row(sc, iw0,iw1,iw2, pi_f,two_pi,
                       angles[r3], angles[r3+1], angles[r3+2], mask[r2], mask[r2+1],
                       q0,q1,q2, i0,i1,i2);
                out_q[r3+0] = q0; out_q[r3+1] = q1; out_q[r3+2] = q2;
                out_i[r3+0] = i0; out_i[r3+1] = i1; out_i[r3+2] = i2;
            }
            __syncthreads();
        }
    }
}

// VERBATIM from rounds 1/3/4 (absmax == 0.0)
static void fill_params(KParams& p) {
    const double PI_D = 3.141592653589793;
    const int nb[3] = {NB0, NB1, NB2};
    int off = 0;
    for (int d = 0; d < 3; ++d) {
        float w = (float)(2.0 * PI_D / (double)nb[d]);
        for (int k = 0; k < nb[d]; ++k) {
            volatile float t = w * ((float)k + 0.5f);
            volatile float c = (float)(-PI_D) + t;
            p.c[off + k] = c;
        }
        p.inv_w[d] = (float)((double)nb[d] / (2.0 * PI_D));
        off += nb[d];
    }
}

extern "C" void kernel_launch(void* const* d_in, const int* in_sizes, int n_in,
                              void* d_out, int out_size, void* d_ws, size_t ws_size,
                              hipStream_t stream) {
    const float* angles = (const float*)d_in[0];
    const int*   mask   = (const int*)d_in[1];
    float* out = (float*)d_out;

    const int total = in_sizes[0];   // nrows * 3
    const int nrows = total / 3;
    float* out_q = out;              // quantized (nrows,3) f32
    float* out_i = out + total;      // indices (nrows,3), written as f32 values

    KParams p;
    fill_params(p);

    int blocks = (nrows + 1023) / 1024;   // 8192 for 4096x2048
    if (blocks < 1) blocks = 1;

    hipLaunchKernelGGL(cyclicvq_kernel, dim3(blocks), dim3(256), 0, stream,
                       angles, mask, out_q, out_i, nrows, p);
}

// Round 6
// 299.028 us; speedup vs baseline: 1.1880x; 1.1880x over previous
//
#include <hip/hip_runtime.h>

typedef float v4f __attribute__((ext_vector_type(4)));
typedef int   v4i __attribute__((ext_vector_type(4)));

#define NB0 24
#define NB1 12
#define NB2 16
#define NC_TOTAL (NB0 + NB1 + NB2)   // 52

struct KParams {
    float c[NC_TOTAL];   // bin centers, host-computed — bit-exact vs JAX f32 (proven r1/r3/r4/r5)
    float inv_w[3];
};

// ---- numeric path: VERBATIM from rounds 1/3/4/5 (absmax == 0.0) — do not touch ----
__device__ __forceinline__ float geo_dist(float a, float c, float two_pi) {
    float diff = fabsf(a - c);
    float alt  = two_pi - diff;
    return fminf(diff, alt);
}

template <int N>
__device__ __forceinline__ void quant1(float a, const float* __restrict__ sc,
                                       float inv_w, float pi_f, float two_pi,
                                       int& idx_out, float& q_out) {
    float u = (a + pi_f) * inv_w;
    int k = (int)floorf(u);
    k = (k < 0) ? 0 : ((k > N - 1) ? (N - 1) : k);
    int km = (k == 0) ? (N - 1) : (k - 1);
    int kp = (k == N - 1) ? 0 : (k + 1);

    float dk = geo_dist(a, sc[k],  two_pi);
    float dm = geo_dist(a, sc[km], two_pi);
    float dp = geo_dist(a, sc[kp], two_pi);

    int best = k; float bd = dk;
    if (dm < bd || (dm == bd && km < best)) { bd = dm; best = km; }
    if (dp < bd || (dp == bd && kp < best)) { bd = dp; best = kp; }

    idx_out = best;
    float t = sc[best] - a;
    q_out = a + t;
}

__device__ __forceinline__ void do_row(const float* __restrict__ sc,
                                       float iw0, float iw1, float iw2,
                                       float pi_f, float two_pi,
                                       float a0, float a1, float a2, int mt_i, int mr_i,
                                       float& q0, float& q1, float& q2,
                                       float& i0, float& i1, float& i2) {
    int b0, b1, b2; float t0, t1, t2;
    quant1<NB0>(a0, sc,             iw0, pi_f, two_pi, b0, t0);
    quant1<NB1>(a1, sc + NB0,       iw1, pi_f, two_pi, b1, t1);
    quant1<NB2>(a2, sc + NB0 + NB1, iw2, pi_f, two_pi, b2, t2);
    bool mt = (mt_i != 0), mr = (mr_i != 0);
    q0 = mt ? 0.0f : t0;
    q1 = mr ? 0.0f : t1;
    q2 = t2;
    i0 = mt ? (float)NB0 : (float)b0;
    i1 = mr ? (float)NB1 : (float)b1;
    i2 = (float)b2;
}
// ---------------------------------------------------------------------------

// Wave geometry identical to r4: 64 lanes x 4 rows = 256 rows/wave, 4 waves/block.
// Each wave uses ONLY its private 6 KiB LDS region -> no cross-wave sharing ->
// no __syncthreads needed per chunk. wave_barrier() = free compile-time ordering
// fence; LDS is in-order per wave; compiler inserts lgkmcnt for aliasing deps.
#define WAVE_LDS 6144

__global__ void __launch_bounds__(256) cyclicvq_kernel(
    const float* __restrict__ angles,
    const int*   __restrict__ mask,
    float* __restrict__ out_q,
    float* __restrict__ out_i,
    int nrows, KParams p)
{
    __shared__ float sc[NC_TOTAL];
    __shared__ unsigned char smem[4 * WAVE_LDS];
    if (threadIdx.x < NC_TOTAL) sc[threadIdx.x] = p.c[threadIdx.x];
    __syncthreads();   // ONLY block barrier: publish sc to all waves

    const float pi_f   = (float)3.141592653589793;
    const float two_pi = (float)6.283185307179586;
    const float iw0 = p.inv_w[0], iw1 = p.inv_w[1], iw2 = p.inv_w[2];

    const int wave = threadIdx.x >> 6;
    const int lane = threadIdx.x & 63;
    const int block_row0 = blockIdx.x << 10;          // 1024 rows per block

    if (block_row0 + 1024 <= nrows) {
        // ------------- fast path: coalesced via wave-private LDS transpose -------------
        const int wave_row0 = block_row0 + (wave << 8);
        const int ga = (wave_row0 * 3) >> 2;          // float4 index into angles/outputs
        const int gm = (wave_row0 >> 1);              // int4 index into mask

        const v4f* av = (const v4f*)angles;
        v4f A0 = __builtin_nontemporal_load(av + ga + lane);
        v4f A1 = __builtin_nontemporal_load(av + ga + 64 + lane);
        v4f A2 = __builtin_nontemporal_load(av + ga + 128 + lane);

        const v4i* mv = (const v4i*)mask;
        v4i M0 = __builtin_nontemporal_load(mv + gm + 2 * lane);
        v4i M1 = __builtin_nontemporal_load(mv + gm + 2 * lane + 1);

        unsigned char* wbase = smem + wave * WAVE_LDS;
        v4f* sA = (v4f*)wbase;
        sA[lane]       = A0;
        sA[64 + lane]  = A1;
        sA[128 + lane] = A2;
        __builtin_amdgcn_wave_barrier();   // order: stage writes before strided reads

        const float* fA = (const float*)wbase;
        v4f a0 = ((const v4f*)(fA + 12 * lane))[0];
        v4f a1 = ((const v4f*)(fA + 12 * lane))[1];
        v4f a2 = ((const v4f*)(fA + 12 * lane))[2];

        float q00,q01,q02,i00,i01,i02;
        float q10,q11,q12,i10,i11,i12;
        float q20,q21,q22,i20,i21,i22;
        float q30,q31,q32,i30,i31,i32;
        do_row(sc, iw0,iw1,iw2, pi_f,two_pi, a0.x, a0.y, a0.z, M0.x, M0.y,
               q00,q01,q02, i00,i01,i02);
        do_row(sc, iw0,iw1,iw2, pi_f,two_pi, a0.w, a1.x, a1.y, M0.z, M0.w,
               q10,q11,q12, i10,i11,i12);
        do_row(sc, iw0,iw1,iw2, pi_f,two_pi, a1.z, a1.w, a2.x, M1.x, M1.y,
               q20,q21,q22, i20,i21,i22);
        do_row(sc, iw0,iw1,iw2, pi_f,two_pi, a2.y, a2.z, a2.w, M1.z, M1.w,
               q30,q31,q32, i30,i31,i32);

        // strided writes: lane x overwrites exactly its own read bytes (Q aliases A)
        float* fQ = (float*)wbase;
        float* fI = (float*)(wbase + 3072);
        __builtin_amdgcn_wave_barrier();   // order: strided reads before aliasing writes
        ((v4f*)(fQ + 12 * lane))[0] = (v4f){q00,q01,q02,q10};
        ((v4f*)(fQ + 12 * lane))[1] = (v4f){q11,q12,q20,q21};
        ((v4f*)(fQ + 12 * lane))[2] = (v4f){q22,q30,q31,q32};
        ((v4f*)(fI + 12 * lane))[0] = (v4f){i00,i01,i02,i10};
        ((v4f*)(fI + 12 * lane))[1] = (v4f){i11,i12,i20,i21};
        ((v4f*)(fI + 12 * lane))[2] = (v4f){i22,i30,i31,i32};
        __builtin_amdgcn_wave_barrier();   // order: strided writes before linear readback

        const v4f* sQ = (const v4f*)wbase;
        const v4f* sI = (const v4f*)(wbase + 3072);
        v4f* oq = (v4f*)out_q;
        v4f* oi = (v4f*)out_i;
        __builtin_nontemporal_store(sQ[lane],        oq + ga + lane);
        __builtin_nontemporal_store(sQ[64 + lane],   oq + ga + 64 + lane);
        __builtin_nontemporal_store(sQ[128 + lane],  oq + ga + 128 + lane);
        __builtin_nontemporal_store(sI[lane],        oi + ga + lane);
        __builtin_nontemporal_store(sI[64 + lane],   oi + ga + 64 + lane);
        __builtin_nontemporal_store(sI[128 + lane],  oi + ga + 128 + lane);
    } else {
        // ------------- tail path: scalar (not taken at 4096x2048) --------------
        for (int row = block_row0 + (int)threadIdx.x; row < nrows; row += 256) {
            long long r3 = (long long)row * 3;
            long long r2 = (long long)row * 2;
            float q0,q1,q2,i0,i1,i2;
            do_row(sc, iw0,iw1,iw2, pi_f,two_pi,
                   angles[r3], angles[r3+1], angles[r3+2], mask[r2], mask[r2+1],
                   q0,q1,q2, i0,i1,i2);
            out_q[r3+0] = q0; out_q[r3+1] = q1; out_q[r3+2] = q2;
            out_i[r3+0] = i0; out_i[r3+1] = i1; out_i[r3+2] = i2;
        }
    }
}

// VERBATIM from rounds 1/3/4/5 (absmax == 0.0)
static void fill_params(KParams& p) {
    const double PI_D = 3.141592653589793;
    const int nb[3] = {NB0, NB1, NB2};
    int off = 0;
    for (int d = 0; d < 3; ++d) {
        float w = (float)(2.0 * PI_D / (double)nb[d]);
        for (int k = 0; k < nb[d]; ++k) {
            volatile float t = w * ((float)k + 0.5f);
            volatile float c = (float)(-PI_D) + t;
            p.c[off + k] = c;
        }
        p.inv_w[d] = (float)((double)nb[d] / (2.0 * PI_D));
        off += nb[d];
    }
}

extern "C" void kernel_launch(void* const* d_in, const int* in_sizes, int n_in,
                              void* d_out, int out_size, void* d_ws, size_t ws_size,
                              hipStream_t stream) {
    const float* angles = (const float*)d_in[0];
    const int*   mask   = (const int*)d_in[1];
    float* out = (float*)d_out;

    const int total = in_sizes[0];   // nrows * 3
    const int nrows = total / 3;
    float* out_q = out;              // quantized (nrows,3) f32
    float* out_i = out + total;      // indices (nrows,3), written as f32 values

    KParams p;
    fill_params(p);

    int blocks = (nrows + 1023) / 1024;   // 8192 for 4096x2048
    if (blocks < 1) blocks = 1;

    hipLaunchKernelGGL(cyclicvq_kernel, dim3(blocks), dim3(256), 0, stream,
                       angles, mask, out_q, out_i, nrows, p);
}